// Round 2
// baseline (303.485 us; speedup 1.0000x reference)
//
#include <hip/hip_runtime.h>

namespace {

constexpr int C = 19;
constexpr int H = 512;
constexpr int W = 1024;
constexpr float EPS = 1e-3f;

// One block per (class c in 1..18, row h). Each thread loads one float4 of
// pred and one int4 of target (256 threads * 4 = W = 1024).
__global__ __launch_bounds__(256) void dice_rows_kernel(
    const float* __restrict__ pred, const int* __restrict__ target,
    float* __restrict__ accum)
{
    const int bx  = blockIdx.x;
    const int c   = (bx % (C - 1)) + 1;   // classes 1..18 (class 0 skipped)
    const int h   = bx / (C - 1);
    const int tid = threadIdx.x;

    // last batch element only: pred[3, c, h, :], target[3, h, :]
    const float4* prow = reinterpret_cast<const float4*>(
        pred + (((size_t)3 * C + c) * H + h) * (size_t)W);
    const int4* trow = reinterpret_cast<const int4*>(
        target + ((size_t)3 * H + h) * (size_t)W);

    const float4 p  = prow[tid];
    const int4   tg = trow[tid];

    float a = 0.f, b = 0.f, cnt = 0.f;
    if (tg.x == c) { a += p.x; cnt += 1.f; }  b += p.x * p.x;
    if (tg.y == c) { a += p.y; cnt += 1.f; }  b += p.y * p.y;
    if (tg.z == c) { a += p.z; cnt += 1.f; }  b += p.z * p.z;
    if (tg.w == c) { a += p.w; cnt += 1.f; }  b += p.w * p.w;

    // wave64 butterfly reduce
    #pragma unroll
    for (int off = 32; off >= 1; off >>= 1) {
        a   += __shfl_down(a,   off, 64);
        b   += __shfl_down(b,   off, 64);
        cnt += __shfl_down(cnt, off, 64);
    }

    __shared__ float sa[4], sb[4], sc[4];
    const int wid = tid >> 6;
    if ((tid & 63) == 0) { sa[wid] = a; sb[wid] = b; sc[wid] = cnt; }
    __syncthreads();

    if (tid == 0) {
        const float A  = sa[0] + sa[1] + sa[2] + sa[3];
        const float B  = sb[0] + sb[1] + sb[2] + sb[3];
        const float Cn = sc[0] + sc[1] + sc[2] + sc[3];
        // loss(c,h) = 1 - 2*A/(B + Cn);  B carries +EPS, Cn carries +EPS
        const float contrib = A / (B + Cn + 2.0f * EPS);
        atomicAdd(accum, contrib);
    }
}

__global__ void finalize_kernel(const float* __restrict__ accum,
                                float* __restrict__ out)
{
    // sum_{c=1..18} mean_h (1 - 2*a/(b+c)) = 18 - (2/H) * accum
    out[0] = (float)(C - 1) - (2.0f / (float)H) * accum[0];
}

} // namespace

extern "C" void kernel_launch(void* const* d_in, const int* in_sizes, int n_in,
                              void* d_out, int out_size, void* d_ws, size_t ws_size,
                              hipStream_t stream)
{
    const float* pred   = (const float*)d_in[0];
    const int*   target = (const int*)d_in[1];
    float*       out    = (float*)d_out;
    float*       accum  = (float*)d_ws;   // d_ws is poisoned 0xAA each call — zero it

    hipMemsetAsync(accum, 0, sizeof(float), stream);
    dice_rows_kernel<<<(C - 1) * H, 256, 0, stream>>>(pred, target, accum);
    finalize_kernel<<<1, 1, 0, stream>>>(accum, out);
}

// Round 3
// 190.755 us; speedup vs baseline: 1.5910x; 1.5910x over previous
//
#include <hip/hip_runtime.h>

namespace {

constexpr int C = 19;
constexpr int H = 512;
constexpr int W = 1024;
constexpr int NROWS = (C - 1) * H;        // 9216 (class,row) pairs, classes 1..18
constexpr int ROWS_PER_BLOCK = 4;         // one row per wave, 4 waves/block
constexpr int NBLOCKS = NROWS / ROWS_PER_BLOCK;  // 2304
constexpr float EPS = 1e-3f;

// Each wave (64 lanes) owns one (c,h) row: 64 lanes * float4 = 1024 = W.
// Row id r = h*18 + (c-1) so the 4 waves of a block share (mostly) the same
// target row -> L1/L2 reuse. Block writes ONE partial sum to partial[bid]
// (plain store, no atomics -> no same-address serialization).
__global__ __launch_bounds__(256) void dice_rows_kernel(
    const float* __restrict__ pred, const int* __restrict__ target,
    float* __restrict__ partial)
{
    const int tid  = threadIdx.x;
    const int wid  = tid >> 6;
    const int lane = tid & 63;
    const int r    = blockIdx.x * ROWS_PER_BLOCK + wid;  // [0, 9216)
    const int c    = (r % (C - 1)) + 1;                  // class 1..18
    const int h    = r / (C - 1);

    // last batch element only: pred[3, c, h, :], target[3, h, :]
    const float4* prow = reinterpret_cast<const float4*>(
        pred + (((size_t)3 * C + c) * H + h) * (size_t)W);
    const int4* trow = reinterpret_cast<const int4*>(
        target + ((size_t)3 * H + h) * (size_t)W);

    const float4 p  = prow[lane];
    const int4   tg = trow[lane];

    float a = 0.f, b = 0.f, cnt = 0.f;
    if (tg.x == c) { a += p.x; cnt += 1.f; }  b += p.x * p.x;
    if (tg.y == c) { a += p.y; cnt += 1.f; }  b += p.y * p.y;
    if (tg.z == c) { a += p.z; cnt += 1.f; }  b += p.z * p.z;
    if (tg.w == c) { a += p.w; cnt += 1.f; }  b += p.w * p.w;

    // wave64 butterfly reduce (whole row lives in this wave)
    #pragma unroll
    for (int off = 32; off >= 1; off >>= 1) {
        a   += __shfl_down(a,   off, 64);
        b   += __shfl_down(b,   off, 64);
        cnt += __shfl_down(cnt, off, 64);
    }

    __shared__ float s[ROWS_PER_BLOCK];
    if (lane == 0) s[wid] = a / (b + cnt + 2.0f * EPS);
    __syncthreads();

    if (tid == 0)
        partial[blockIdx.x] = s[0] + s[1] + s[2] + s[3];
}

// Single block reduces the 2304 partials.
__global__ __launch_bounds__(256) void finalize_kernel(
    const float* __restrict__ partial, float* __restrict__ out)
{
    const int tid = threadIdx.x;
    float sum = 0.f;
    #pragma unroll
    for (int i = tid; i < NBLOCKS; i += 256) sum += partial[i];

    #pragma unroll
    for (int off = 32; off >= 1; off >>= 1)
        sum += __shfl_down(sum, off, 64);

    __shared__ float s[4];
    if ((tid & 63) == 0) s[tid >> 6] = sum;
    __syncthreads();

    if (tid == 0) {
        const float acc = s[0] + s[1] + s[2] + s[3];
        // sum_{c=1..18} mean_h (1 - 2*a/(b+cnt)) = 18 - (2/H) * acc
        out[0] = (float)(C - 1) - (2.0f / (float)H) * acc;
    }
}

} // namespace

extern "C" void kernel_launch(void* const* d_in, const int* in_sizes, int n_in,
                              void* d_out, int out_size, void* d_ws, size_t ws_size,
                              hipStream_t stream)
{
    const float* pred    = (const float*)d_in[0];
    const int*   target  = (const int*)d_in[1];
    float*       out     = (float*)d_out;
    float*       partial = (float*)d_ws;   // 2304 floats; fully overwritten each call

    dice_rows_kernel<<<NBLOCKS, 256, 0, stream>>>(pred, target, partial);
    finalize_kernel<<<1, 256, 0, stream>>>(partial, out);
}